// Round 14
// baseline (648.170 us; speedup 1.0000x reference)
//
#include <hip/hip_runtime.h>
#include <hip/hip_bf16.h>

// TinyLocalWindowAttention on MI355X (gfx950)
// x:(32,256,112,112) f32, 7x7 windows; ONE BLOCK = VERTICAL window pair
// (wh=2k, 2k+1), processed sequentially with cross-window load pipelining.
// Vertical neighbors share ZERO cache lines (lines run along W) -> sequential
// processing cannot break line-merging (R12's horizontal-adjacency trap).
// Grid 4096, 4 waves, LDS 32KB static + 16KB dynamic = 48KB -> 3 blocks/CU
// (measured optimum: FETCH doubles per extra block/CU; R13 closed the axis).
// Compute = R11: own-head qkv, all attention fragments in registers via
// ds_bpermute; 3 barriers/window. Window 1's x-loads issue right after
// window 0's qkv (sched_barrier pins issue) and land during attention.

typedef short bf16x8 __attribute__((ext_vector_type(8)));   // 8 bf16 (4 VGPRs)
typedef float f32x4 __attribute__((ext_vector_type(4)));

static __device__ __forceinline__ unsigned int cvt2(float a, float b) {
    float2 t; t.x = a; t.y = b;
    __hip_bfloat162 hh = __float22bfloat162_rn(t);
    unsigned int u; __builtin_memcpy(&u, &hh, 4); return u;
}
static __device__ __forceinline__ float bf2f(unsigned int hs) {
    return __uint_as_float(hs << 16);
}

#define WQ_ELEMS 65536LL
#define WP_ELEMS 32768LL

// ---- pre-pass: Wqkv[256][256], Wproj[128][256] f32 -> bf16 fragment arrays.
// frag[((tile*KT+kt)*64+lane)*8+j] = W[kt*32+(lane>>4)*8+j][tile*16+(lane&15)]
__global__ void prep_weights(const float* __restrict__ Wqkv,
                             const float* __restrict__ Wproj,
                             unsigned short* __restrict__ wq,
                             unsigned short* __restrict__ wp) {
    int tid = blockIdx.x * 256 + threadIdx.x;
    if (tid < 8192) {                         // 16 tiles * 8 ktiles * 64 lanes
        int lane = tid & 63, f = tid >> 6;
        int kt = f & 7, nt = f >> 3;
        int kbase = kt * 32 + (lane >> 4) * 8;
        int col = nt * 16 + (lane & 15);
        uint4 u;
        u.x = cvt2(Wqkv[(kbase + 0) * 256 + col], Wqkv[(kbase + 1) * 256 + col]);
        u.y = cvt2(Wqkv[(kbase + 2) * 256 + col], Wqkv[(kbase + 3) * 256 + col]);
        u.z = cvt2(Wqkv[(kbase + 4) * 256 + col], Wqkv[(kbase + 5) * 256 + col]);
        u.w = cvt2(Wqkv[(kbase + 6) * 256 + col], Wqkv[(kbase + 7) * 256 + col]);
        *reinterpret_cast<uint4*>(&wq[(long long)tid * 8]) = u;
    } else if (tid < 12288) {                 // 16 tiles * 4 ktiles * 64 lanes
        int i2 = tid - 8192;
        int lane = i2 & 63, f = i2 >> 6;
        int kt = f & 3, nt = f >> 2;
        int kbase = kt * 32 + (lane >> 4) * 8;
        int col = nt * 16 + (lane & 15);
        uint4 u;
        u.x = cvt2(Wproj[(kbase + 0) * 256 + col], Wproj[(kbase + 1) * 256 + col]);
        u.y = cvt2(Wproj[(kbase + 2) * 256 + col], Wproj[(kbase + 3) * 256 + col]);
        u.z = cvt2(Wproj[(kbase + 4) * 256 + col], Wproj[(kbase + 5) * 256 + col]);
        u.w = cvt2(Wproj[(kbase + 6) * 256 + col], Wproj[(kbase + 7) * 256 + col]);
        *reinterpret_cast<uint4*>(&wp[(long long)i2 * 8]) = u;
    }
}

// LDS: static A (32KB): xa[64][256] (re-staged for window 1)
//      dynamic OS (16KB): o_s[64][128]
// swizzle: elem(row,col,W) = row*W + (((col>>3) ^ (row&7))<<3) + (col&7)

__global__ __launch_bounds__(256, 3) void win_attn(
    const float* __restrict__ x,
    const unsigned short* __restrict__ wfq,
    const unsigned short* __restrict__ wfp,
    const float* __restrict__ bqkv,
    const float* __restrict__ bproj,
    float* __restrict__ out)
{
    __shared__ __align__(16) unsigned short A[16384];
    extern __shared__ unsigned short OS[];    // 16 KB: o_s[64][128]

    const int tid  = threadIdx.x;
    const int lane = tid & 63;
    const int wave = tid >> 6;
    const int lr   = lane & 15;       // row/col within 16-tile
    const int kg   = lane >> 4;       // k-group (0..3)
    const int h    = wave;            // head

    // block -> vertical pair: lin = (b, kh, ww); windows (b, 2kh+w, ww)
    const int bid = (int)blockIdx.x;
    const int lin = (bid & 7) * 512 + (bid >> 3);   // XCD-contiguous
    const int b   = lin >> 7;
    const int rem = lin & 127;
    const int kh  = rem >> 4;
    const int ww  = rem & 15;
    const int xbase = (b * 256) * 12544 + (kh * 14) * 112 + ww * 7;
    const int loff  = (lane / 7) * 112 + (lane % 7);   // token geometry (lane<49)

    // biases: q/k swapped (4 consecutive channels/lane -> float4);
    // v unswapped (channel-in-tile = lr -> scalar); proj swapped (float4)
    const float4 bq = *reinterpret_cast<const float4*>(&bqkv[h * 16 + kg * 4]);
    const float4 bk = *reinterpret_cast<const float4*>(&bqkv[64 + h * 16 + kg * 4]);
    const float bv0 = bqkv[128 + h * 32 + lr];
    const float bv1 = bqkv[128 + h * 32 + 16 + lr];
    float4 bp4[4];
    #pragma unroll
    for (int i = 0; i < 4; ++i)
        bp4[i] = *reinterpret_cast<const float4*>(&bproj[wave * 64 + i * 16 + kg * 4]);

    // zero-pad token rows 49..63 ONCE (staging never touches them)
    {
        uint4 z4 = uint4{0u, 0u, 0u, 0u};
        for (int i = tid; i < 480; i += 256)
            reinterpret_cast<uint4*>(&A[49 * 256])[i] = z4;
    }
    // prologue: stage window 0 (deep unroll -> more loads in flight)
    if (lane < 49) {
        const int lb = xbase + loff;
        #pragma unroll 8
        for (int it = 0; it < 16; ++it) {
            const int c0 = wave * 64 + it * 4;
            const float v0 = x[lb + (c0 + 0) * 12544];
            const float v1 = x[lb + (c0 + 1) * 12544];
            const float v2 = x[lb + (c0 + 2) * 12544];
            const float v3 = x[lb + (c0 + 3) * 12544];
            uint2 pk; pk.x = cvt2(v0, v1); pk.y = cvt2(v2, v3);
            const int e = lane * 256 + (((c0 >> 3) ^ (lane & 7)) << 3) + (c0 & 7);
            *reinterpret_cast<uint2*>(&A[e]) = pk;
        }
    }

    const int a0 = (((kg & 1) * 2) * 16 + lr) * 4;
    const int a1 = (((kg & 1) * 2 + 1) * 16 + lr) * 4;
    const bool act = (lane < 32);
    const bf16x8 zf = {0, 0, 0, 0, 0, 0, 0, 0};
    const float C = 0.25f * 1.44269504f;    // SCALE * log2(e)

    float xr[8][4];                          // window-1 prefetch (w=0 body only)
    const int lbn = xbase + 784 + loff;      // window 1 base (7 rows below)

    #pragma unroll
    for (int w = 0; w < 2; ++w) {
        __syncthreads();   // B_a: xa(w) ready

        // ---- qkv for THIS head: tiles tq=h, tk=4+h, tv0=8+2h, tv1=9+2h ----
        f32x4 aq[4], ak[4], av[4][2];
        #pragma unroll
        for (int t = 0; t < 4; ++t) {
            aq[t] = f32x4{0.f, 0.f, 0.f, 0.f};
            ak[t] = f32x4{0.f, 0.f, 0.f, 0.f};
            av[t][0] = f32x4{0.f, 0.f, 0.f, 0.f};
            av[t][1] = f32x4{0.f, 0.f, 0.f, 0.f};
        }
        {
            const int tq = h, tk = 4 + h, tv0 = 8 + 2 * h, tv1 = 9 + 2 * h;
            #pragma unroll
            for (int kt = 0; kt < 8; ++kt) {
                bf16x8 a[4];
                #pragma unroll
                for (int m = 0; m < 4; ++m) {
                    const int row = lr + 16 * m;
                    const int ch  = (kt * 4 + kg) ^ (row & 7);
                    a[m] = *reinterpret_cast<const bf16x8*>(&A[row * 256 + ch * 8]);
                }
                const bf16x8 bwq = *reinterpret_cast<const bf16x8*>(&wfq[((tq * 8 + kt) * 64 + lane) * 8]);
                const bf16x8 bwk = *reinterpret_cast<const bf16x8*>(&wfq[((tk * 8 + kt) * 64 + lane) * 8]);
                const bf16x8 bw0 = *reinterpret_cast<const bf16x8*>(&wfq[((tv0 * 8 + kt) * 64 + lane) * 8]);
                const bf16x8 bw1 = *reinterpret_cast<const bf16x8*>(&wfq[((tv1 * 8 + kt) * 64 + lane) * 8]);
                #pragma unroll
                for (int t = 0; t < 4; ++t) {
                    aq[t] = __builtin_amdgcn_mfma_f32_16x16x32_bf16(bwq, a[t], aq[t], 0, 0, 0);
                    ak[t] = __builtin_amdgcn_mfma_f32_16x16x32_bf16(bwk, a[t], ak[t], 0, 0, 0);
                    av[t][0] = __builtin_amdgcn_mfma_f32_16x16x32_bf16(a[t], bw0, av[t][0], 0, 0, 0);
                    av[t][1] = __builtin_amdgcn_mfma_f32_16x16x32_bf16(a[t], bw1, av[t][1], 0, 0, 0);
                }
            }
        }
        __syncthreads();   // B_b: all waves done reading xa

        // ---- issue window 1's x loads NOW (pinned); land during attention ----
        if (w == 0) {
            if (lane < 49) {
                #pragma unroll
                for (int it = 0; it < 8; ++it) {
                    const int c0 = wave * 64 + it * 4;
                    xr[it][0] = x[lbn + (c0 + 0) * 12544];
                    xr[it][1] = x[lbn + (c0 + 1) * 12544];
                    xr[it][2] = x[lbn + (c0 + 2) * 12544];
                    xr[it][3] = x[lbn + (c0 + 3) * 12544];
                }
            }
            __builtin_amdgcn_sched_barrier(0);   // pin issue before attention
        }

        // ---- in-register fragment builds (bpermute; no LDS memory) ----
        bf16x8 qf[4], kf[4];
        #pragma unroll
        for (int t = 0; t < 4; ++t) {
            const unsigned int d0 = cvt2(aq[t][0] + bq.x, aq[t][1] + bq.y);
            const unsigned int d1 = cvt2(aq[t][2] + bq.z, aq[t][3] + bq.w);
            union { unsigned int u[4]; bf16x8 v; } f;
            f.u[0] = (unsigned)__builtin_amdgcn_ds_bpermute(a0, (int)d0);
            f.u[1] = (unsigned)__builtin_amdgcn_ds_bpermute(a0, (int)d1);
            f.u[2] = (unsigned)__builtin_amdgcn_ds_bpermute(a1, (int)d0);
            f.u[3] = (unsigned)__builtin_amdgcn_ds_bpermute(a1, (int)d1);
            qf[t] = act ? f.v : zf;
        }
        #pragma unroll
        for (int t = 0; t < 4; ++t) {
            const unsigned int d0 = cvt2(ak[t][0] + bk.x, ak[t][1] + bk.y);
            const unsigned int d1 = cvt2(ak[t][2] + bk.z, ak[t][3] + bk.w);
            union { unsigned int u[4]; bf16x8 v; } f;
            f.u[0] = (unsigned)__builtin_amdgcn_ds_bpermute(a0, (int)d0);
            f.u[1] = (unsigned)__builtin_amdgcn_ds_bpermute(a0, (int)d1);
            f.u[2] = (unsigned)__builtin_amdgcn_ds_bpermute(a1, (int)d0);
            f.u[3] = (unsigned)__builtin_amdgcn_ds_bpermute(a1, (int)d1);
            kf[t] = act ? f.v : zf;
        }
        bf16x8 vb[2][2];
        {
            unsigned int ve0[4][2], ve1[4][2];
            #pragma unroll
            for (int tm = 0; tm < 4; ++tm)
                #pragma unroll
                for (int cn = 0; cn < 2; ++cn) {
                    const float bv = cn ? bv1 : bv0;
                    ve0[tm][cn] = cvt2(av[tm][cn][0] + bv, av[tm][cn][1] + bv);
                    ve1[tm][cn] = cvt2(av[tm][cn][2] + bv, av[tm][cn][3] + bv);
                }
            const bool lo2 = (kg < 2);
            #pragma unroll
            for (int kt = 0; kt < 2; ++kt)
                #pragma unroll
                for (int nt = 0; nt < 2; ++nt) {
                    const int ta = 2 * kt, tb = 2 * kt + 1;
                    const unsigned int u0a = (unsigned)__builtin_amdgcn_ds_bpermute(a0, (int)ve0[ta][nt]);
                    const unsigned int u0b = (unsigned)__builtin_amdgcn_ds_bpermute(a0, (int)ve0[tb][nt]);
                    const unsigned int u1a = (unsigned)__builtin_amdgcn_ds_bpermute(a0, (int)ve1[ta][nt]);
                    const unsigned int u1b = (unsigned)__builtin_amdgcn_ds_bpermute(a0, (int)ve1[tb][nt]);
                    const unsigned int u2a = (unsigned)__builtin_amdgcn_ds_bpermute(a1, (int)ve0[ta][nt]);
                    const unsigned int u2b = (unsigned)__builtin_amdgcn_ds_bpermute(a1, (int)ve0[tb][nt]);
                    const unsigned int u3a = (unsigned)__builtin_amdgcn_ds_bpermute(a1, (int)ve1[ta][nt]);
                    const unsigned int u3b = (unsigned)__builtin_amdgcn_ds_bpermute(a1, (int)ve1[tb][nt]);
                    union { unsigned int u[4]; bf16x8 v; } f;
                    f.u[0] = lo2 ? u0a : u0b;
                    f.u[1] = lo2 ? u1a : u1b;
                    f.u[2] = lo2 ? u2a : u2b;
                    f.u[3] = lo2 ? u3a : u3b;
                    vb[kt][nt] = f.v;
                }
        }

        // ---- attention: S^T = mfma(K,Q); in-register softmax; PV swapped ----
        f32x4 oacc[4][2];
        #pragma unroll
        for (int qn = 0; qn < 4; ++qn) {
            oacc[qn][0] = f32x4{0.f, 0.f, 0.f, 0.f};
            oacc[qn][1] = f32x4{0.f, 0.f, 0.f, 0.f};
        }
        float rsv[4];
        #pragma unroll
        for (int qn = 0; qn < 4; ++qn) {
            f32x4 s[4];
            #pragma unroll
            for (int km = 0; km < 4; ++km) {
                f32x4 z = f32x4{0.f, 0.f, 0.f, 0.f};
                s[km] = __builtin_amdgcn_mfma_f32_16x16x32_bf16(kf[km], qf[qn], z, 0, 0, 0);
            }
            float e[4][4];
            float sum = 0.f;
            #pragma unroll
            for (int km = 0; km < 4; ++km)
                #pragma unroll
                for (int r = 0; r < 4; ++r) {
                    float v = __builtin_amdgcn_exp2f(s[km][r] * C);
                    if (km == 3 && !(kg == 0 && r == 0)) v = 0.f;   // k-token 48 only
                    e[km][r] = v;
                    sum += v;
                }
            unsigned int D[4][2];
            #pragma unroll
            for (int km = 0; km < 4; ++km) {
                D[km][0] = cvt2(e[km][0], e[km][1]);
                D[km][1] = cvt2(e[km][2], e[km][3]);
            }
            sum += __shfl_xor(sum, 16, 64);
            sum += __shfl_xor(sum, 32, 64);
            rsv[qn] = __builtin_amdgcn_rcpf(sum);

            #pragma unroll
            for (int kt = 0; kt < 2; ++kt) {
                const int klo = 2 * kt, khi = 2 * kt + 1;
                const unsigned int t0 = (unsigned)__builtin_amdgcn_ds_bpermute(a0, (int)D[klo][0]);
                const unsigned int u0 = (unsigned)__builtin_amdgcn_ds_bpermute(a0, (int)D[khi][0]);
                const unsigned int t1 = (unsigned)__builtin_amdgcn_ds_bpermute(a0, (int)D[klo][1]);
                const unsigned int u1 = (unsigned)__builtin_amdgcn_ds_bpermute(a0, (int)D[khi][1]);
                const unsigned int t2 = (unsigned)__builtin_amdgcn_ds_bpermute(a1, (int)D[klo][0]);
                const unsigned int u2 = (unsigned)__builtin_amdgcn_ds_bpermute(a1, (int)D[khi][0]);
                const unsigned int t3 = (unsigned)__builtin_amdgcn_ds_bpermute(a1, (int)D[klo][1]);
                const unsigned int u3 = (unsigned)__builtin_amdgcn_ds_bpermute(a1, (int)D[khi][1]);
                union { unsigned int u[4]; bf16x8 v; } pu;
                pu.u[0] = (kg < 2) ? t0 : u0;
                pu.u[1] = (kg < 2) ? t1 : u1;
                pu.u[2] = (kg < 2) ? t2 : u2;
                pu.u[3] = (kg < 2) ? t3 : u3;
                oacc[qn][0] = __builtin_amdgcn_mfma_f32_16x16x32_bf16(vb[kt][0], pu.v, oacc[qn][0], 0, 0, 0);
                oacc[qn][1] = __builtin_amdgcn_mfma_f32_16x16x32_bf16(vb[kt][1], pu.v, oacc[qn][1], 0, 0, 0);
            }
        }

        // o_s[64][128] in OS: tok=qn*16+lr, c = h*32+nt*16+kg*4(+r)
        #pragma unroll
        for (int qn = 0; qn < 4; ++qn) {
            const float rs = rsv[qn];
            const int tok = qn * 16 + lr;
            #pragma unroll
            for (int nt = 0; nt < 2; ++nt) {
                const int cch = h * 4 + nt * 2 + (kg >> 1);
                const int clo = (kg & 1) * 4;
                uint2 pk;
                pk.x = cvt2(oacc[qn][nt][0] * rs, oacc[qn][nt][1] * rs);
                pk.y = cvt2(oacc[qn][nt][2] * rs, oacc[qn][nt][3] * rs);
                *reinterpret_cast<uint2*>(
                    &OS[tok * 128 + ((cch ^ (tok & 7)) << 3) + clo]) = pk;
            }
        }

        // ---- stage window 1's xa into A (w=0 only; xa dead since B_b) ----
        if (w == 0 && lane < 49) {
            #pragma unroll
            for (int it = 0; it < 8; ++it) {
                const int c0 = wave * 64 + it * 4;
                uint2 pk;
                pk.x = cvt2(xr[it][0], xr[it][1]);
                pk.y = cvt2(xr[it][2], xr[it][3]);
                const int e = lane * 256 + (((c0 >> 3) ^ (lane & 7)) << 3) + (c0 & 7);
                *reinterpret_cast<uint2*>(&A[e]) = pk;
            }
            #pragma unroll
            for (int it = 8; it < 16; ++it) {
                const int c0 = wave * 64 + it * 4;
                const float v0 = x[lbn + (c0 + 0) * 12544];
                const float v1 = x[lbn + (c0 + 1) * 12544];
                const float v2 = x[lbn + (c0 + 2) * 12544];
                const float v3 = x[lbn + (c0 + 3) * 12544];
                uint2 pk; pk.x = cvt2(v0, v1); pk.y = cvt2(v2, v3);
                const int e = lane * 256 + (((c0 >> 3) ^ (lane & 7)) << 3) + (c0 & 7);
                *reinterpret_cast<uint2*>(&A[e]) = pk;
            }
        }
        __syncthreads();   // B_c: o_s ready (and xa(w1) staged)

        // ---- proj (swapped): OUT^T = mfma(Wp-tile(ci), o-tile(tj)) ----
        f32x4 pc[4][4];
        #pragma unroll
        for (int m = 0; m < 4; ++m)
            #pragma unroll
            for (int nn = 0; nn < 4; ++nn)
                pc[m][nn] = f32x4{0.f, 0.f, 0.f, 0.f};

        #pragma unroll
        for (int kt = 0; kt < 4; ++kt) {
            bf16x8 a[4], bw[4];
            #pragma unroll
            for (int tj = 0; tj < 4; ++tj) {
                const int row = lr + 16 * tj;
                const int ch = (kt * 4 + kg) ^ (row & 7);
                a[tj] = *reinterpret_cast<const bf16x8*>(&OS[row * 128 + ch * 8]);
            }
            #pragma unroll
            for (int ci = 0; ci < 4; ++ci) {
                const int nt = wave * 4 + ci;
                bw[ci] = *reinterpret_cast<const bf16x8*>(&wfp[((nt * 4 + kt) * 64 + lane) * 8]);
            }
            #pragma unroll
            for (int ci = 0; ci < 4; ++ci)
                #pragma unroll
                for (int tj = 0; tj < 4; ++tj)
                    pc[ci][tj] = __builtin_amdgcn_mfma_f32_16x16x32_bf16(bw[ci], a[tj], pc[ci][tj], 0, 0, 0);
        }

        // ---- direct f32 stores from pc (col=token, rows=4 consecutive ch) ----
        #pragma unroll
        for (int ci = 0; ci < 4; ++ci) {
            float* opc = out + xbase + w * 784 + (wave * 64 + ci * 16 + kg * 4) * 12544;
            #pragma unroll
            for (int tj = 0; tj < 4; ++tj) {
                if (tj < 3 || lr == 0) {
                    const int tok = tj * 16 + lr;
                    const int trow = tok / 7;
                    const int tcol = tok - trow * 7;
                    float* op = opc + trow * 112 + tcol;
                    op[0]         = pc[ci][tj][0] + bp4[ci].x;
                    op[12544]     = pc[ci][tj][1] + bp4[ci].y;
                    op[2 * 12544] = pc[ci][tj][2] + bp4[ci].z;
                    op[3 * 12544] = pc[ci][tj][3] + bp4[ci].w;
                }
            }
        }
    }
}

extern "C" void kernel_launch(void* const* d_in, const int* in_sizes, int n_in,
                              void* d_out, int out_size, void* d_ws, size_t ws_size,
                              hipStream_t stream) {
    const float* x     = (const float*)d_in[0];
    const float* Wqkv  = (const float*)d_in[1];
    const float* bqkv  = (const float*)d_in[2];
    const float* Wproj = (const float*)d_in[3];
    const float* bproj = (const float*)d_in[4];
    float* out = (float*)d_out;

    unsigned short* wfq = (unsigned short*)d_ws;
    unsigned short* wfp = wfq + WQ_ELEMS;

    prep_weights<<<48, 256, 0, stream>>>(Wqkv, Wproj, wfq, wfp);
    // 16 KB dynamic LDS = o_s; total 48 KB -> exactly 3 blocks/CU
    win_attn<<<4096, 256, 16384, stream>>>(x, wfq, wfp, bqkv, bproj, out);
}